// Round 21
// baseline (3347.257 us; speedup 1.0000x reference)
//
#include <hip/hip_runtime.h>
#include <hip/hip_fp16.h>

#define NN 1048576   // nodes
#define NE 8388608   // edges
#define NG 16384     // graphs
#define NBUCK 4096   // dst buckets (256 nodes each)
#define BSH 8        // bucket shift (node = bucket*256 + dlocal)
#define PBLK 128     // partition blocks
#define EPB (NE / PBLK)  // edges per partition block = 65536

typedef _Float16 half8 __attribute__((ext_vector_type(8)));
typedef float f32x16 __attribute__((ext_vector_type(16)));

// ---------------- node embedding: hA = f16(x @ W_emb^T + b_emb) ----------------
__global__ __launch_bounds__(256) void k_embed(const float* __restrict__ x,
    const float* __restrict__ W, const float* __restrict__ b, __half* __restrict__ h) {
  __shared__ float sW[160];
  __shared__ float sb[32];
  int t = threadIdx.x;
  if (t < 160) sW[t] = W[t];
  if (t < 32) sb[t] = b[t];
  __syncthreads();
  int idx = blockIdx.x * 256 + t;      // (node, channel)
  int c = idx & 31, n = idx >> 5;
  const float* xr = x + n * 5;
  float acc = sb[c];
#pragma unroll
  for (int k = 0; k < 5; ++k) acc = fmaf(xr[k], sW[c * 5 + k], acc);
  h[idx] = __float2half(acc);
}

// ---------------- radix pass 1: per-(block,bucket) histogram ----------------
__global__ __launch_bounds__(256) void k_pcnt(const int* __restrict__ dst, int* __restrict__ hist) {
  __shared__ int lh[NBUCK];            // 16 KB
  int t = threadIdx.x;
#pragma unroll
  for (int k = 0; k < 16; ++k) lh[t + k * 256] = 0;
  __syncthreads();
  int base = blockIdx.x * EPB;
  for (int e = base + t; e < base + EPB; e += 256)
    atomicAdd(&lh[dst[e] >> BSH], 1);
  __syncthreads();
#pragma unroll
  for (int k = 0; k < 16; ++k) {
    int b = t + k * 256;
    hist[b * PBLK + blockIdx.x] = lh[b];           // assign, no atomics
  }
}

// ---------------- radix pass 2a: per-bucket row scan (PBLK cols) + totals ----------------
__global__ __launch_bounds__(128) void k_scanA(int* __restrict__ hist, int* __restrict__ tot) {
  __shared__ int s2[128];
  int b = blockIdx.x, t = threadIdx.x;
  int v = hist[b * PBLK + t];
  s2[t] = v; __syncthreads();
  for (int st = 1; st < 128; st <<= 1) {
    int a = (t >= st) ? s2[t - st] : 0; __syncthreads(); s2[t] += a; __syncthreads();
  }
  hist[b * PBLK + t] = s2[t] - v;
  if (t == 127) tot[b] = s2[127];
}

// ---------------- radix pass 2b: scan 4096 bucket totals -> gbase ----------------
__global__ __launch_bounds__(256) void k_scanB(const int* __restrict__ tot, int* __restrict__ gbase) {
  __shared__ int s2[256];
  int t = threadIdx.x;
  int v[16]; int tsum = 0;
#pragma unroll
  for (int j = 0; j < 16; ++j) { v[j] = tot[t * 16 + j]; tsum += v[j]; }
  s2[t] = tsum; __syncthreads();
  for (int st = 1; st < 256; st <<= 1) {
    int a = (t >= st) ? s2[t - st] : 0; __syncthreads(); s2[t] += a; __syncthreads();
  }
  int ex = s2[t] - tsum;
#pragma unroll
  for (int j = 0; j < 16; ++j) { gbase[t * 16 + j] = ex; ex += v[j]; }
  if (t == 255) gbase[NBUCK] = ex;                  // == NE
}

// ---- radix pass 3: partition; record = ((src<<8)|dlocal, w_f32bits), bucket-grouped ----
__global__ __launch_bounds__(256) void k_part(const int* __restrict__ ei, const float* __restrict__ ew,
                                              const int* __restrict__ hist, const int* __restrict__ gbase,
                                              uint2* __restrict__ bsw) {
  __shared__ int cur[NBUCK];           // 16 KB
  int t = threadIdx.x, blk = blockIdx.x;
#pragma unroll
  for (int k = 0; k < 16; ++k) {
    int b = t + k * 256;
    cur[b] = gbase[b] + hist[b * PBLK + blk];
  }
  __syncthreads();
  int base = blk * EPB;
  for (int e = base + t; e < base + EPB; e += 256) {
    int src = ei[e];
    int d   = ei[NE + e];
    unsigned wb = __float_as_uint(ew[e]);
    int b = d >> BSH;
    int pos = atomicAdd(&cur[b], 1);
    bsw[pos] = make_uint2(((unsigned)src << BSH) | (unsigned)(d & 255), wb);
  }
}

// ---------------- graph rowptr from sorted batch ----------------
__global__ __launch_bounds__(256) void k_gbound(const int* __restrict__ batch, int* __restrict__ gptr) {
  int n = blockIdx.x * 256 + threadIdx.x;
  int b = batch[n];
  int prev = (n == 0) ? -1 : batch[n - 1];
  for (int g = prev + 1; g <= b; ++g) gptr[g] = n;
  if (n == NN - 1) {
    for (int g = b + 1; g <= NG; ++g) gptr[g] = NN;
  }
}

// ------ PUSH-style agglin: one block per 256-node bucket; LDS f32 accumulator tile ------
// consumes bucket-grouped records directly (no per-node CSR, no fillD). 8-deep gather.
__global__ __launch_bounds__(256) void k_agglin(
    const int* __restrict__ gbase, const uint2* __restrict__ bsw,
    const __half* __restrict__ hIn, const float* __restrict__ Wrel,
    const float* __restrict__ brel, const float* __restrict__ Wroot,
    __half* __restrict__ hPre, double* __restrict__ stats) {
  __shared__ float agg[256 * 33];     // padded stride 33: bank = (row+col)%32 (33.8 KB)
  __shared__ uint2 sE[256];           // staged records
  __shared__ double rS[256], rQ[256];
  int t = threadIdx.x;
  int wv = t >> 6, lane = t & 63;
  int c = lane & 31, hi = lane >> 5, grp = t >> 5;
  int b = blockIdx.x;
  int beg = gbase[b], end = gbase[b + 1];

  // B fragments in registers: B[k][c], k = 16m + hi*8 + j
  half8 bfr[4];
#pragma unroll
  for (int m = 0; m < 4; ++m)
#pragma unroll
    for (int j = 0; j < 8; ++j) {
      int k = 16 * m + hi * 8 + j;
      float w = (k < 32) ? Wrel[c * 32 + k] : Wroot[c * 32 + (k - 32)];
      bfr[m][j] = (_Float16)w;
    }
  float bias = brel[c];

  // zero accumulator tile
  for (int i = t; i < 256 * 33; i += 256) agg[i] = 0.f;
  __syncthreads();

  // ---- edge loop: 8 groups x 32-record chunks ----
  for (int j0 = beg + grp * 32; j0 < end; j0 += 8 * 32) {
    int m_ = end - j0; if (m_ > 32) m_ = 32;
    uint2 cw = make_uint2(0u, 0u);               // pad: dl=0, src=0, w=+0 (adds 0 to node 0)
    if (c < m_) cw = bsw[j0 + c];
    sE[t] = cw;                                  // same-wave LDS: no barrier
    int mm = (m_ + 7) & ~7;
    for (int i = 0; i < mm; i += 8) {
      const uint4* eb4 = (const uint4*)&sE[grp * 32 + i];
      uint4 q0 = eb4[0], q1 = eb4[1], q2 = eb4[2], q3 = eb4[3];
      // 8 independent 2B gathers in flight
      float h0 = __half2float(hIn[(size_t)(q0.x >> BSH) * 32 + c]);
      float h1 = __half2float(hIn[(size_t)(q0.z >> BSH) * 32 + c]);
      float h2 = __half2float(hIn[(size_t)(q1.x >> BSH) * 32 + c]);
      float h3 = __half2float(hIn[(size_t)(q1.z >> BSH) * 32 + c]);
      float h4 = __half2float(hIn[(size_t)(q2.x >> BSH) * 32 + c]);
      float h5 = __half2float(hIn[(size_t)(q2.z >> BSH) * 32 + c]);
      float h6 = __half2float(hIn[(size_t)(q3.x >> BSH) * 32 + c]);
      float h7 = __half2float(hIn[(size_t)(q3.z >> BSH) * 32 + c]);
      atomicAdd(&agg[(q0.x & 255) * 33 + c], __uint_as_float(q0.y) * h0);
      atomicAdd(&agg[(q0.z & 255) * 33 + c], __uint_as_float(q0.w) * h1);
      atomicAdd(&agg[(q1.x & 255) * 33 + c], __uint_as_float(q1.y) * h2);
      atomicAdd(&agg[(q1.z & 255) * 33 + c], __uint_as_float(q1.w) * h3);
      atomicAdd(&agg[(q2.x & 255) * 33 + c], __uint_as_float(q2.y) * h4);
      atomicAdd(&agg[(q2.z & 255) * 33 + c], __uint_as_float(q2.w) * h5);
      atomicAdd(&agg[(q3.x & 255) * 33 + c], __uint_as_float(q3.y) * h6);
      atomicAdd(&agg[(q3.z & 255) * 33 + c], __uint_as_float(q3.w) * h7);
    }
  }
  __syncthreads();

  // ---- MFMA epilogue: 8 tiles of 32 nodes; wave wv owns tiles 2wv, 2wv+1 ----
  float aS = 0.f, aQ = 0.f;
#pragma unroll
  for (int tt = 0; tt < 2; ++tt) {
    int nloc = (wv * 2 + tt) * 32;               // local node base of this tile
    int nglob = b * 256 + nloc;
    f32x16 d;
#pragma unroll
    for (int r = 0; r < 16; ++r) d[r] = bias;
#pragma unroll
    for (int m = 0; m < 4; ++m) {
      half8 a;
      if (m < 2) {
        const float* row = &agg[(nloc + c) * 33 + 16 * m + hi * 8];
#pragma unroll
        for (int j = 0; j < 8; ++j) a[j] = (_Float16)row[j];
      } else {
        int chb = 16 * (m - 2) + hi * 8;
        a = *(const half8*)(hIn + (size_t)(nglob + c) * 32 + chb);
      }
      d = __builtin_amdgcn_mfma_f32_32x32x16_f16(a, bfr[m], d, 0, 0, 0);
    }
    // D: col=lane&31, row=(r&3)+8*(r>>2)+4*hi
#pragma unroll
    for (int r = 0; r < 16; ++r) {
      int node = (r & 3) + 8 * (r >> 2) + 4 * hi;
      float v = d[r];
      hPre[(size_t)(nglob + node) * 32 + c] = __float2half(v);
      aS += v; aQ += v * v;
    }
  }
  rS[t] = (double)aS; rQ[t] = (double)aQ;
  __syncthreads();
  for (int s = 128; s >= 32; s >>= 1) {
    if (t < s) { rS[t] += rS[t + s]; rQ[t] += rQ[t + s]; }
    __syncthreads();
  }
  if (t < 32) {
    atomicAdd(&stats[t], rS[t]);
    atomicAdd(&stats[32 + t], rQ[t]);
  }
}

// ---------------- finalize BN ----------------
__global__ void k_bnfin(const double* __restrict__ stats, const float* __restrict__ gamma,
                        const float* __restrict__ beta, float* __restrict__ ss) {
  int c = threadIdx.x;
  double mean = stats[c] * (1.0 / NN);
  double var = stats[32 + c] * (1.0 / NN) - mean * mean;
  float scale = gamma[c] * (float)(1.0 / sqrt(var + 1e-5));
  ss[c] = scale;
  ss[32 + c] = beta[c] - (float)mean * scale;
}

// ---------------- BN apply + ReLU (layer 1) ----------------
__global__ __launch_bounds__(256) void k_apply(const __half* __restrict__ in,
    const float* __restrict__ ss, __half* __restrict__ outp) {
  __shared__ float s0[32], s1[32];
  int t = threadIdx.x;
  if (t < 32) { s0[t] = ss[t]; s1[t] = ss[32 + t]; }
  __syncthreads();
  int idx = blockIdx.x * 256 + t;
  int c = idx & 31;
  float v = fmaxf(fmaf(__half2float(in[idx]), s0[c], s1[c]), 0.f);
  outp[idx] = __float2half(v);
}

// ------- layer-2 BN apply + ReLU + segment-max pool (half2, 4 node-slots) -------
__global__ __launch_bounds__(256) void k_pool(const __half* __restrict__ hB,
    const float* __restrict__ ss, const int* __restrict__ gptr, float* __restrict__ pooled) {
  int t = threadIdx.x;
  int wv = t >> 6, lane = t & 63;
  int p = lane >> 4, cl = lane & 15;          // 4 nodes in flight, 2 ch/lane
  float s0x = ss[2 * cl], s0y = ss[2 * cl + 1];
  float s1x = ss[32 + 2 * cl], s1y = ss[32 + 2 * cl + 1];
  int g = blockIdx.x * 4 + wv;                // grid 4096 x 4 waves = NG exactly
  int a = gptr[g], b = gptr[g + 1];
  float mx = 0.f, my = 0.f;                   // post-ReLU max >= 0
  for (int n = a + p; n < b; n += 4) {
    float2 hv = __half22float2(*(const __half2*)(hB + (size_t)n * 32 + 2 * cl));
    mx = fmaxf(mx, fmaf(hv.x, s0x, s1x));
    my = fmaxf(my, fmaf(hv.y, s0y, s1y));
  }
  mx = fmaxf(mx, __shfl_xor(mx, 16, 64)); my = fmaxf(my, __shfl_xor(my, 16, 64));
  mx = fmaxf(mx, __shfl_xor(mx, 32, 64)); my = fmaxf(my, __shfl_xor(my, 32, 64));
  if (p == 0) *(float2*)&pooled[g * 32 + 2 * cl] = make_float2(mx, my);
}

// ---------------- MLP head ----------------
__global__ __launch_bounds__(256) void k_head(const float* __restrict__ pooled,
    const float* __restrict__ W1, const float* __restrict__ b1,
    const float* __restrict__ W2, const float* __restrict__ b2, float* __restrict__ out) {
  __shared__ float sW1[64 * 33], sW2[10 * 65], sb1[64], sb2[10];
  __shared__ float sHid[4][64];
  int t = threadIdx.x;
  for (int i = t; i < 2048; i += 256) sW1[(i >> 5) * 33 + (i & 31)] = W1[i];
  for (int i = t; i < 640; i += 256) sW2[(i >> 6) * 65 + (i & 63)] = W2[i];
  if (t < 64) sb1[t] = b1[t];
  if (t < 10) sb2[t] = b2[t];
  __syncthreads();
  int w = t >> 6, lane = t & 63;
  for (int g = blockIdx.x * 4 + w; g < NG; g += gridDim.x * 4) {
    float pv = (lane < 32) ? pooled[g * 32 + lane] : 0.f;
    float acc = sb1[lane];
#pragma unroll
    for (int k = 0; k < 32; ++k)
      acc = fmaf(__shfl(pv, k, 64), sW1[lane * 33 + k], acc);
    acc = fmaxf(acc, 0.f);
    sHid[w][lane] = acc;
    __syncthreads();
    if (lane < 10) {
      float o = sb2[lane];
#pragma unroll
      for (int j = 0; j < 64; ++j) o = fmaf(sHid[w][j], sW2[lane * 65 + j], o);
      out[g * 10 + lane] = o;
    }
    __syncthreads();
  }
}

extern "C" void kernel_launch(void* const* d_in, const int* in_sizes, int n_in,
                              void* d_out, int out_size, void* d_ws, size_t ws_size,
                              hipStream_t stream) {
  const float* x      = (const float*)d_in[0];
  const int*   ei     = (const int*)d_in[1];
  const float* ea     = (const float*)d_in[2];
  const int*   batch  = (const int*)d_in[3];
  const float* W_emb  = (const float*)d_in[4];
  const float* b_emb  = (const float*)d_in[5];
  const float* W_rel  = (const float*)d_in[6];
  const float* b_rel  = (const float*)d_in[7];
  const float* W_root = (const float*)d_in[8];
  const float* gamma  = (const float*)d_in[9];
  const float* beta   = (const float*)d_in[10];
  const float* W1     = (const float*)d_in[11];
  const float* b1     = (const float*)d_in[12];
  const float* W2     = (const float*)d_in[13];
  const float* b2     = (const float*)d_in[14];
  float* out = (float*)d_out;

  // ---- workspace layout (~199 MiB of 256 MiB; bsw lives through both layers) ----
  char* ws = (char*)d_ws;
  size_t off = 0;
  __half* hA    = (__half*)(ws + off); off += (size_t)NN * 32 * 2;          // 64 MiB
  __half* hB    = (__half*)(ws + off); off += (size_t)NN * 32 * 2;          // 64 MiB
  uint2*  bsw   = (uint2*)(ws + off);  off += (size_t)NE * 8;               // 64 MiB
  int*    hist  = (int*)(ws + off);    off += (size_t)NBUCK * PBLK * 4;     // 2 MiB
  int*    tot   = (int*)(ws + off);    off += NBUCK * 4;                    // 16 KiB
  int*    gbase = (int*)(ws + off);    off += (NBUCK + 64) * 4;             // ~16 KiB
  int*    gptr  = (int*)(ws + off);    off += ((size_t)NG + 64) * 4;
  float*  pooled= (float*)(ws + off);                                        // 2 MiB
  double* stats = (double*)d_out;                   // overwritten by k_head later
  float*  ss0   = (float*)((char*)d_out + 512);
  float*  ss1   = (float*)((char*)d_out + 768);

  k_embed<<<NN * 32 / 256, 256, 0, stream>>>(x, W_emb, b_emb, hA);

  // ---- radix-partition build: bucket-grouped records only (no per-node CSR) ----
  k_pcnt <<<PBLK, 256, 0, stream>>>(ei + NE, hist);
  k_scanA<<<NBUCK, 128, 0, stream>>>(hist, tot);
  k_scanB<<<1, 256, 0, stream>>>(tot, gbase);
  k_part <<<PBLK, 256, 0, stream>>>(ei, ea, hist, gbase, bsw);
  k_gbound<<<NN / 256, 256, 0, stream>>>(batch, gptr);

  // ---- layer 1: agglin(hA -> hB), BN stats, apply BN+ReLU (hB -> hA) ----
  (void)hipMemsetAsync(stats, 0, 64 * 8, stream);
  k_agglin<<<NBUCK, 256, 0, stream>>>(gbase, bsw, hA, W_rel, b_rel, W_root, hB, stats);
  k_bnfin<<<1, 32, 0, stream>>>(stats, gamma, beta, ss0);
  k_apply<<<NN * 32 / 256, 256, 0, stream>>>(hB, ss0, hA);

  // ---- layer 2: agglin(hA -> hB), BN stats, fused pool ----
  (void)hipMemsetAsync(stats, 0, 64 * 8, stream);
  k_agglin<<<NBUCK, 256, 0, stream>>>(gbase, bsw, hA, W_rel + 1024, b_rel + 32,
                                      W_root + 1024, hB, stats);
  k_bnfin<<<1, 32, 0, stream>>>(stats, gamma + 32, beta + 32, ss1);

  k_pool<<<NG / 4, 256, 0, stream>>>(hB, ss1, gptr, pooled);
  k_head<<<1024, 256, 0, stream>>>(pooled, W1, b1, W2, b2, out);
}

// Round 22
// 1114.596 us; speedup vs baseline: 3.0031x; 3.0031x over previous
//
#include <hip/hip_runtime.h>
#include <hip/hip_fp16.h>

#define NN 1048576   // nodes
#define NE 8388608   // edges
#define NG 16384     // graphs
#define NBUCK 4096   // dst buckets (256 nodes each)
#define BSH 8        // bucket shift (node = bucket*256 + dlocal)
#define PBLK 128     // partition blocks
#define EPB (NE / PBLK)  // edges per partition block = 65536
#define SCAP 2600    // LDS record capacity per bucket (mean 2048, +12 sigma)

typedef _Float16 half8 __attribute__((ext_vector_type(8)));
typedef float f32x16 __attribute__((ext_vector_type(16)));

// ---------------- node embedding: hA = f16(x @ W_emb^T + b_emb) ----------------
__global__ __launch_bounds__(256) void k_embed(const float* __restrict__ x,
    const float* __restrict__ W, const float* __restrict__ b, __half* __restrict__ h) {
  __shared__ float sW[160];
  __shared__ float sb[32];
  int t = threadIdx.x;
  if (t < 160) sW[t] = W[t];
  if (t < 32) sb[t] = b[t];
  __syncthreads();
  int idx = blockIdx.x * 256 + t;      // (node, channel)
  int c = idx & 31, n = idx >> 5;
  const float* xr = x + n * 5;
  float acc = sb[c];
#pragma unroll
  for (int k = 0; k < 5; ++k) acc = fmaf(xr[k], sW[c * 5 + k], acc);
  h[idx] = __float2half(acc);
}

// ---------------- radix pass 1: per-(block,bucket) histogram ----------------
__global__ __launch_bounds__(256) void k_pcnt(const int* __restrict__ dst, int* __restrict__ hist) {
  __shared__ int lh[NBUCK];            // 16 KB
  int t = threadIdx.x;
#pragma unroll
  for (int k = 0; k < 16; ++k) lh[t + k * 256] = 0;
  __syncthreads();
  int base = blockIdx.x * EPB;
  for (int e = base + t; e < base + EPB; e += 256)
    atomicAdd(&lh[dst[e] >> BSH], 1);
  __syncthreads();
#pragma unroll
  for (int k = 0; k < 16; ++k) {
    int b = t + k * 256;
    hist[b * PBLK + blockIdx.x] = lh[b];           // assign, no atomics
  }
}

// ---------------- radix pass 2a: per-bucket row scan (PBLK cols) + totals ----------------
__global__ __launch_bounds__(128) void k_scanA(int* __restrict__ hist, int* __restrict__ tot) {
  __shared__ int s2[128];
  int b = blockIdx.x, t = threadIdx.x;
  int v = hist[b * PBLK + t];
  s2[t] = v; __syncthreads();
  for (int st = 1; st < 128; st <<= 1) {
    int a = (t >= st) ? s2[t - st] : 0; __syncthreads(); s2[t] += a; __syncthreads();
  }
  hist[b * PBLK + t] = s2[t] - v;
  if (t == 127) tot[b] = s2[127];
}

// ---------------- radix pass 2b: scan 4096 bucket totals -> gbase ----------------
__global__ __launch_bounds__(256) void k_scanB(const int* __restrict__ tot, int* __restrict__ gbase) {
  __shared__ int s2[256];
  int t = threadIdx.x;
  int v[16]; int tsum = 0;
#pragma unroll
  for (int j = 0; j < 16; ++j) { v[j] = tot[t * 16 + j]; tsum += v[j]; }
  s2[t] = tsum; __syncthreads();
  for (int st = 1; st < 256; st <<= 1) {
    int a = (t >= st) ? s2[t - st] : 0; __syncthreads(); s2[t] += a; __syncthreads();
  }
  int ex = s2[t] - tsum;
#pragma unroll
  for (int j = 0; j < 16; ++j) { gbase[t * 16 + j] = ex; ex += v[j]; }
  if (t == 255) gbase[NBUCK] = ex;                  // == NE
}

// ---- radix pass 3: partition; record = ((src<<8)|dlocal, w_f32bits), bucket-grouped ----
__global__ __launch_bounds__(256) void k_part(const int* __restrict__ ei, const float* __restrict__ ew,
                                              const int* __restrict__ hist, const int* __restrict__ gbase,
                                              uint2* __restrict__ bsw) {
  __shared__ int cur[NBUCK];           // 16 KB
  int t = threadIdx.x, blk = blockIdx.x;
#pragma unroll
  for (int k = 0; k < 16; ++k) {
    int b = t + k * 256;
    cur[b] = gbase[b] + hist[b * PBLK + blk];
  }
  __syncthreads();
  int base = blk * EPB;
  for (int e = base + t; e < base + EPB; e += 256) {
    int src = ei[e];
    int d   = ei[NE + e];
    unsigned wb = __float_as_uint(ew[e]);
    int b = d >> BSH;
    int pos = atomicAdd(&cur[b], 1);
    bsw[pos] = make_uint2(((unsigned)src << BSH) | (unsigned)(d & 255), wb);
  }
}

// ------- CSR finalize: LDS-staged per-bucket sort -> rowptr + L2-local colw scatter -------
__global__ __launch_bounds__(256) void k_fillD2(const int* __restrict__ gbase, const uint2* __restrict__ bsw,
                                                int* __restrict__ rowptr, uint2* __restrict__ colw) {
  __shared__ uint2 rec[SCAP];          // 20.8 KB record staging
  __shared__ int loc[256];
  __shared__ int s2[256];
  int t = threadIdx.x, b = blockIdx.x;
  int beg = gbase[b], end = gbase[b + 1], gb = beg;
  int cnt = end - beg;
  bool staged = (cnt <= SCAP);         // block-uniform; fallback path for impossible overflow
  loc[t] = 0;
  if (staged) {
    for (int i = t; i < cnt; i += 256) rec[i] = bsw[beg + i];   // one coalesced read
  }
  __syncthreads();
  for (int i = t; i < cnt; i += 256) {
    unsigned rx = staged ? rec[i].x : bsw[beg + i].x;
    atomicAdd(&loc[rx & 255], 1);
  }
  __syncthreads();
  int v = loc[t];
  s2[t] = v; __syncthreads();
  for (int st = 1; st < 256; st <<= 1) {
    int a = (t >= st) ? s2[t - st] : 0; __syncthreads(); s2[t] += a; __syncthreads();
  }
  int base_t = s2[t] - v;
  rowptr[(b << BSH) + t] = gb + base_t;            // coalesced rowptr write
  loc[t] = base_t;                                 // running cursor per node
  if (b == NBUCK - 1 && t == 255) rowptr[NN] = NE;
  __syncthreads();
  for (int i = t; i < cnt; i += 256) {
    uint2 r = staged ? rec[i] : bsw[beg + i];
    int p = atomicAdd(&loc[r.x & 255], 1);
    colw[gb + p] = make_uint2(r.x >> BSH, r.y);    // scatter within 16 KB L2-resident span
  }
}

// ---------------- graph rowptr from sorted batch ----------------
__global__ __launch_bounds__(256) void k_gbound(const int* __restrict__ batch, int* __restrict__ gptr) {
  int n = blockIdx.x * 256 + threadIdx.x;
  int b = batch[n];
  int prev = (n == 0) ? -1 : batch[n - 1];
  for (int g = prev + 1; g <= b; ++g) gptr[g] = n;
  if (n == NN - 1) {
    for (int g = b + 1; g <= NG; ++g) gptr[g] = NN;
  }
}

// ------ fused pull-aggregate + MFMA dual-linear + BN stats (EXACT R11/R15 body) ------
__global__ __launch_bounds__(256) void k_agglin(
    const int* __restrict__ rowptr, const uint2* __restrict__ colw,
    const __half* __restrict__ hIn, const float* __restrict__ Wrel,
    const float* __restrict__ brel, const float* __restrict__ Wroot,
    __half* __restrict__ hPre, double* __restrict__ stats) {
  __shared__ __half sA[4][1024];      // per-wave 32x32 f16 agg tile (XOR-swizzled)
  __shared__ uint2 sE[256];           // staged edge records
  __shared__ double rS[256], rQ[256];
  int t = threadIdx.x;
  int wv = t >> 6, lane = t & 63;
  int c = lane & 31, hi = lane >> 5, grp = t >> 5;
  char* myA = (char*)sA[wv];

  // B fragments in registers: B[k][c], k = 16m + hi*8 + j
  half8 bfr[4];
#pragma unroll
  for (int m = 0; m < 4; ++m)
#pragma unroll
    for (int j = 0; j < 8; ++j) {
      int k = 16 * m + hi * 8 + j;
      float w = (k < 32) ? Wrel[c * 32 + k] : Wroot[c * 32 + (k - 32)];
      bfr[m][j] = (_Float16)w;
    }
  float bias = brel[c];
  double aS = 0.0, aQ = 0.0;

  for (int tile = blockIdx.x * 4 + wv; tile < NN / 32; tile += gridDim.x * 4) {
    int nbase = tile * 32;
    // ---- gather: 16 rounds x 2 nodes (one per 32-lane group) ----
    for (int r = 0; r < 16; ++r) {
      int node = 2 * r + hi;
      int n = nbase + node;
      int r0 = rowptr[n], r1 = rowptr[n + 1];
      float acc = 0.f;
      for (int j = r0; j < r1; j += 32) {
        int m_ = r1 - j; if (m_ > 32) m_ = 32;
        uint2 cw = make_uint2(0u, 0u);             // pad: src=0 row, w=+0
        if (c < m_) cw = colw[j + c];
        sE[t] = cw;                                // same-wave LDS
        int mm = (m_ + 7) & ~7;
        for (int i = 0; i < mm; i += 8) {
          const uint4* eb4 = (const uint4*)&sE[grp * 32 + i];
          uint4 q0 = eb4[0], q1 = eb4[1], q2 = eb4[2], q3 = eb4[3];
          // 8 independent 2 B gathers -> 8 loads in flight
          float h0 = __half2float(hIn[(size_t)q0.x * 32 + c]);
          float h1 = __half2float(hIn[(size_t)q0.z * 32 + c]);
          float h2 = __half2float(hIn[(size_t)q1.x * 32 + c]);
          float h3 = __half2float(hIn[(size_t)q1.z * 32 + c]);
          float h4 = __half2float(hIn[(size_t)q2.x * 32 + c]);
          float h5 = __half2float(hIn[(size_t)q2.z * 32 + c]);
          float h6 = __half2float(hIn[(size_t)q3.x * 32 + c]);
          float h7 = __half2float(hIn[(size_t)q3.z * 32 + c]);
          acc = fmaf(__uint_as_float(q0.y), h0, acc);
          acc = fmaf(__uint_as_float(q0.w), h1, acc);
          acc = fmaf(__uint_as_float(q1.y), h2, acc);
          acc = fmaf(__uint_as_float(q1.w), h3, acc);
          acc = fmaf(__uint_as_float(q2.y), h4, acc);
          acc = fmaf(__uint_as_float(q2.w), h5, acc);
          acc = fmaf(__uint_as_float(q3.y), h6, acc);
          acc = fmaf(__uint_as_float(q3.w), h7, acc);
        }
      }
      // write acc to swizzled f16 tile: logical (node, k=c)
      int bw = (node * 64 + c * 2) ^ ((node & 7) << 4);
      *(__half*)(myA + bw) = __float2half(acc);
    }
    // ---- MFMA epilogue (wave-private; same-wave LDS ordering) ----
    f32x16 d;
#pragma unroll
    for (int r = 0; r < 16; ++r) d[r] = bias;
#pragma unroll
    for (int m = 0; m < 4; ++m) {
      half8 a;
      if (m < 2) {
        int node = c;                               // A row = lane&31
        int br = (node * 64 + (16 * m + hi * 8) * 2) ^ ((node & 7) << 4);
        a = *(const half8*)(myA + br);
      } else {
        int chb = 16 * (m - 2) + hi * 8;            // h channel base
        a = *(const half8*)(hIn + (size_t)(nbase + c) * 32 + chb);
      }
      d = __builtin_amdgcn_mfma_f32_32x32x16_f16(a, bfr[m], d, 0, 0, 0);
    }
    // ---- store + BN stats; D: col=lane&31, row=(r&3)+8*(r>>2)+4*hi ----
#pragma unroll
    for (int r = 0; r < 16; ++r) {
      int node = (r & 3) + 8 * (r >> 2) + 4 * hi;
      float v = d[r];
      hPre[(size_t)(nbase + node) * 32 + c] = __float2half(v);
      aS += v; aQ += (double)v * v;
    }
  }
  rS[t] = aS; rQ[t] = aQ;
  __syncthreads();
  for (int s = 128; s >= 32; s >>= 1) {
    if (t < s) { rS[t] += rS[t + s]; rQ[t] += rQ[t + s]; }
    __syncthreads();
  }
  if (t < 32) {
    atomicAdd(&stats[t], rS[t]);
    atomicAdd(&stats[32 + t], rQ[t]);
  }
}

// ---------------- finalize BN ----------------
__global__ void k_bnfin(const double* __restrict__ stats, const float* __restrict__ gamma,
                        const float* __restrict__ beta, float* __restrict__ ss) {
  int c = threadIdx.x;
  double mean = stats[c] * (1.0 / NN);
  double var = stats[32 + c] * (1.0 / NN) - mean * mean;
  float scale = gamma[c] * (float)(1.0 / sqrt(var + 1e-5));
  ss[c] = scale;
  ss[32 + c] = beta[c] - (float)mean * scale;
}

// ---------------- BN apply + ReLU (layer 1) ----------------
__global__ __launch_bounds__(256) void k_apply(const __half* __restrict__ in,
    const float* __restrict__ ss, __half* __restrict__ outp) {
  __shared__ float s0[32], s1[32];
  int t = threadIdx.x;
  if (t < 32) { s0[t] = ss[t]; s1[t] = ss[32 + t]; }
  __syncthreads();
  int idx = blockIdx.x * 256 + t;
  int c = idx & 31;
  float v = fmaxf(fmaf(__half2float(in[idx]), s0[c], s1[c]), 0.f);
  outp[idx] = __float2half(v);
}

// ------- layer-2 BN apply + ReLU + segment-max pool (half2, 4 node-slots) -------
__global__ __launch_bounds__(256) void k_pool(const __half* __restrict__ hB,
    const float* __restrict__ ss, const int* __restrict__ gptr, float* __restrict__ pooled) {
  int t = threadIdx.x;
  int wv = t >> 6, lane = t & 63;
  int p = lane >> 4, cl = lane & 15;          // 4 nodes in flight, 2 ch/lane
  float s0x = ss[2 * cl], s0y = ss[2 * cl + 1];
  float s1x = ss[32 + 2 * cl], s1y = ss[32 + 2 * cl + 1];
  int g = blockIdx.x * 4 + wv;                // grid 4096 x 4 waves = NG exactly
  int a = gptr[g], b = gptr[g + 1];
  float mx = 0.f, my = 0.f;                   // post-ReLU max >= 0
  for (int n = a + p; n < b; n += 4) {
    float2 hv = __half22float2(*(const __half2*)(hB + (size_t)n * 32 + 2 * cl));
    mx = fmaxf(mx, fmaf(hv.x, s0x, s1x));
    my = fmaxf(my, fmaf(hv.y, s0y, s1y));
  }
  mx = fmaxf(mx, __shfl_xor(mx, 16, 64)); my = fmaxf(my, __shfl_xor(my, 16, 64));
  mx = fmaxf(mx, __shfl_xor(mx, 32, 64)); my = fmaxf(my, __shfl_xor(my, 32, 64));
  if (p == 0) *(float2*)&pooled[g * 32 + 2 * cl] = make_float2(mx, my);
}

// ---------------- MLP head ----------------
__global__ __launch_bounds__(256) void k_head(const float* __restrict__ pooled,
    const float* __restrict__ W1, const float* __restrict__ b1,
    const float* __restrict__ W2, const float* __restrict__ b2, float* __restrict__ out) {
  __shared__ float sW1[64 * 33], sW2[10 * 65], sb1[64], sb2[10];
  __shared__ float sHid[4][64];
  int t = threadIdx.x;
  for (int i = t; i < 2048; i += 256) sW1[(i >> 5) * 33 + (i & 31)] = W1[i];
  for (int i = t; i < 640; i += 256) sW2[(i >> 6) * 65 + (i & 63)] = W2[i];
  if (t < 64) sb1[t] = b1[t];
  if (t < 10) sb2[t] = b2[t];
  __syncthreads();
  int w = t >> 6, lane = t & 63;
  for (int g = blockIdx.x * 4 + w; g < NG; g += gridDim.x * 4) {
    float pv = (lane < 32) ? pooled[g * 32 + lane] : 0.f;
    float acc = sb1[lane];
#pragma unroll
    for (int k = 0; k < 32; ++k)
      acc = fmaf(__shfl(pv, k, 64), sW1[lane * 33 + k], acc);
    acc = fmaxf(acc, 0.f);
    sHid[w][lane] = acc;
    __syncthreads();
    if (lane < 10) {
      float o = sb2[lane];
#pragma unroll
      for (int j = 0; j < 64; ++j) o = fmaf(sHid[w][j], sW2[lane * 65 + j], o);
      out[g * 10 + lane] = o;
    }
    __syncthreads();
  }
}

extern "C" void kernel_launch(void* const* d_in, const int* in_sizes, int n_in,
                              void* d_out, int out_size, void* d_ws, size_t ws_size,
                              hipStream_t stream) {
  const float* x      = (const float*)d_in[0];
  const int*   ei     = (const int*)d_in[1];
  const float* ea     = (const float*)d_in[2];
  const int*   batch  = (const int*)d_in[3];
  const float* W_emb  = (const float*)d_in[4];
  const float* b_emb  = (const float*)d_in[5];
  const float* W_rel  = (const float*)d_in[6];
  const float* b_rel  = (const float*)d_in[7];
  const float* W_root = (const float*)d_in[8];
  const float* gamma  = (const float*)d_in[9];
  const float* beta   = (const float*)d_in[10];
  const float* W1     = (const float*)d_in[11];
  const float* b1     = (const float*)d_in[12];
  const float* W2     = (const float*)d_in[13];
  const float* b2     = (const float*)d_in[14];
  float* out = (float*)d_out;

  // ---- workspace layout (~202 MiB of 256 MiB) ----
  char* ws = (char*)d_ws;
  size_t off = 0;
  __half* hA    = (__half*)(ws + off); off += (size_t)NN * 32 * 2;          // 64 MiB
  uint2*  colw  = (uint2*)(ws + off);  off += (size_t)NE * 8;               // 64 MiB
  uint2*  bsw   = (uint2*)(ws + off);                                        // 64 MiB
  __half* hB    = (__half*)(ws + off);                                       // ALIASES bsw (dead before hB written)
  off += (size_t)NE * 8;
  int*    rowptr= (int*)(ws + off);    off += ((size_t)NN + 64) * 4;        // 4 MiB
  int*    hist  = (int*)(ws + off);    off += (size_t)NBUCK * PBLK * 4;     // 2 MiB
  int*    tot   = (int*)(ws + off);    off += NBUCK * 4;                    // 16 KiB
  int*    gbase = (int*)(ws + off);    off += (NBUCK + 64) * 4;             // ~16 KiB
  int*    gptr  = (int*)(ws + off);    off += ((size_t)NG + 64) * 4;
  float*  pooled= (float*)(ws + off);                                        // 2 MiB
  double* stats = (double*)d_out;                   // overwritten by k_head later
  float*  ss0   = (float*)((char*)d_out + 512);
  float*  ss1   = (float*)((char*)d_out + 768);

  k_embed<<<NN * 32 / 256, 256, 0, stream>>>(x, W_emb, b_emb, hA);

  // ---- radix-partition CSR build (4096 buckets; LDS-staged finalize) ----
  k_pcnt <<<PBLK, 256, 0, stream>>>(ei + NE, hist);
  k_scanA<<<NBUCK, 128, 0, stream>>>(hist, tot);
  k_scanB<<<1, 256, 0, stream>>>(tot, gbase);
  k_part <<<PBLK, 256, 0, stream>>>(ei, ea, hist, gbase, bsw);
  k_fillD2<<<NBUCK, 256, 0, stream>>>(gbase, bsw, rowptr, colw);
  k_gbound<<<NN / 256, 256, 0, stream>>>(batch, gptr);

  // ---- layer 1: agglin(hA -> hB), BN stats, apply BN+ReLU (hB -> hA) ----
  (void)hipMemsetAsync(stats, 0, 64 * 8, stream);
  k_agglin<<<2048, 256, 0, stream>>>(rowptr, colw, hA, W_rel, b_rel, W_root, hB, stats);
  k_bnfin<<<1, 32, 0, stream>>>(stats, gamma, beta, ss0);
  k_apply<<<NN * 32 / 256, 256, 0, stream>>>(hB, ss0, hA);

  // ---- layer 2: agglin(hA -> hB), BN stats, fused pool ----
  (void)hipMemsetAsync(stats, 0, 64 * 8, stream);
  k_agglin<<<2048, 256, 0, stream>>>(rowptr, colw, hA, W_rel + 1024, b_rel + 32,
                                     W_root + 1024, hB, stats);
  k_bnfin<<<1, 32, 0, stream>>>(stats, gamma + 32, beta + 32, ss1);

  k_pool<<<NG / 4, 256, 0, stream>>>(hB, ss1, gptr, pooled);
  k_head<<<1024, 256, 0, stream>>>(pooled, W1, b1, W2, b2, out);
}

// Round 23
// 974.977 us; speedup vs baseline: 3.4332x; 1.1432x over previous
//
#include <hip/hip_runtime.h>
#include <hip/hip_fp16.h>

#define NN 1048576   // nodes
#define NE 8388608   // edges
#define NG 16384     // graphs
#define NBUCK 4096   // dst buckets (256 nodes each)
#define BSH 8        // bucket shift (node = bucket*256 + dlocal)
#define PBLK 256     // partition blocks (1 per CU)
#define EPB (NE / PBLK)  // edges per partition block = 32768
#define SCAP 2600    // LDS record capacity per bucket (mean 2048, +12 sigma)

typedef _Float16 half8 __attribute__((ext_vector_type(8)));
typedef float f32x16 __attribute__((ext_vector_type(16)));

// ---------------- node embedding: hA = f16(x @ W_emb^T + b_emb) ----------------
__global__ __launch_bounds__(256) void k_embed(const float* __restrict__ x,
    const float* __restrict__ W, const float* __restrict__ b, __half* __restrict__ h) {
  __shared__ float sW[160];
  __shared__ float sb[32];
  int t = threadIdx.x;
  if (t < 160) sW[t] = W[t];
  if (t < 32) sb[t] = b[t];
  __syncthreads();
  int idx = blockIdx.x * 256 + t;      // (node, channel)
  int c = idx & 31, n = idx >> 5;
  const float* xr = x + n * 5;
  float acc = sb[c];
#pragma unroll
  for (int k = 0; k < 5; ++k) acc = fmaf(xr[k], sW[c * 5 + k], acc);
  h[idx] = __float2half(acc);
}

// ---------------- radix pass 1: per-(block,bucket) histogram (1024 threads) ----------------
__global__ __launch_bounds__(1024) void k_pcnt(const int* __restrict__ dst, int* __restrict__ hist) {
  __shared__ int lh[NBUCK];            // 16 KB
  int t = threadIdx.x;
#pragma unroll
  for (int k = 0; k < 4; ++k) lh[t + k * 1024] = 0;
  __syncthreads();
  int base = blockIdx.x * EPB;
  for (int e = base + t; e < base + EPB; e += 1024)
    atomicAdd(&lh[dst[e] >> BSH], 1);
  __syncthreads();
#pragma unroll
  for (int k = 0; k < 4; ++k) {
    int b = t + k * 1024;
    hist[b * PBLK + blockIdx.x] = lh[b];           // assign, no atomics
  }
}

// ---------------- radix pass 2a: per-bucket row scan (PBLK=256 cols) + totals ----------------
__global__ __launch_bounds__(256) void k_scanA(int* __restrict__ hist, int* __restrict__ tot) {
  __shared__ int s2[256];
  int b = blockIdx.x, t = threadIdx.x;
  int v = hist[b * PBLK + t];
  s2[t] = v; __syncthreads();
  for (int st = 1; st < 256; st <<= 1) {
    int a = (t >= st) ? s2[t - st] : 0; __syncthreads(); s2[t] += a; __syncthreads();
  }
  hist[b * PBLK + t] = s2[t] - v;
  if (t == 255) tot[b] = s2[255];
}

// ---------------- radix pass 2b: scan 4096 bucket totals -> gbase ----------------
__global__ __launch_bounds__(256) void k_scanB(const int* __restrict__ tot, int* __restrict__ gbase) {
  __shared__ int s2[256];
  int t = threadIdx.x;
  int v[16]; int tsum = 0;
#pragma unroll
  for (int j = 0; j < 16; ++j) { v[j] = tot[t * 16 + j]; tsum += v[j]; }
  s2[t] = tsum; __syncthreads();
  for (int st = 1; st < 256; st <<= 1) {
    int a = (t >= st) ? s2[t - st] : 0; __syncthreads(); s2[t] += a; __syncthreads();
  }
  int ex = s2[t] - tsum;
#pragma unroll
  for (int j = 0; j < 16; ++j) { gbase[t * 16 + j] = ex; ex += v[j]; }
  if (t == 255) gbase[NBUCK] = ex;                  // == NE
}

// ---- radix pass 3: partition (1024 threads, 16 waves/CU); 8-record full-line runs ----
__global__ __launch_bounds__(1024) void k_part(const int* __restrict__ ei, const float* __restrict__ ew,
                                               const int* __restrict__ hist, const int* __restrict__ gbase,
                                               uint2* __restrict__ bsw) {
  __shared__ int cur[NBUCK];           // 16 KB
  int t = threadIdx.x, blk = blockIdx.x;
#pragma unroll
  for (int k = 0; k < 4; ++k) {
    int b = t + k * 1024;
    cur[b] = gbase[b] + hist[b * PBLK + blk];
  }
  __syncthreads();
  int base = blk * EPB;
  for (int e = base + t; e < base + EPB; e += 1024) {
    int src = ei[e];
    int d   = ei[NE + e];
    unsigned wb = __float_as_uint(ew[e]);
    int b = d >> BSH;
    int pos = atomicAdd(&cur[b], 1);
    bsw[pos] = make_uint2(((unsigned)src << BSH) | (unsigned)(d & 255), wb);
  }
}

// ------- CSR finalize: LDS-staged per-bucket sort -> rowptr + L2-local colw scatter -------
__global__ __launch_bounds__(256) void k_fillD2(const int* __restrict__ gbase, const uint2* __restrict__ bsw,
                                                int* __restrict__ rowptr, uint2* __restrict__ colw) {
  __shared__ uint2 rec[SCAP];          // 20.8 KB record staging
  __shared__ int loc[256];
  __shared__ int s2[256];
  int t = threadIdx.x, b = blockIdx.x;
  int beg = gbase[b], end = gbase[b + 1], gb = beg;
  int cnt = end - beg;
  bool staged = (cnt <= SCAP);         // block-uniform; fallback path for impossible overflow
  loc[t] = 0;
  if (staged) {
    for (int i = t; i < cnt; i += 256) rec[i] = bsw[beg + i];   // one coalesced read
  }
  __syncthreads();
  for (int i = t; i < cnt; i += 256) {
    unsigned rx = staged ? rec[i].x : bsw[beg + i].x;
    atomicAdd(&loc[rx & 255], 1);
  }
  __syncthreads();
  int v = loc[t];
  s2[t] = v; __syncthreads();
  for (int st = 1; st < 256; st <<= 1) {
    int a = (t >= st) ? s2[t - st] : 0; __syncthreads(); s2[t] += a; __syncthreads();
  }
  int base_t = s2[t] - v;
  rowptr[(b << BSH) + t] = gb + base_t;            // coalesced rowptr write
  loc[t] = base_t;                                 // running cursor per node
  if (b == NBUCK - 1 && t == 255) rowptr[NN] = NE;
  __syncthreads();
  for (int i = t; i < cnt; i += 256) {
    uint2 r = staged ? rec[i] : bsw[beg + i];
    int p = atomicAdd(&loc[r.x & 255], 1);
    colw[gb + p] = make_uint2(r.x >> BSH, r.y);    // scatter within 16 KB L2-resident span
  }
}

// ---------------- graph rowptr from sorted batch ----------------
__global__ __launch_bounds__(256) void k_gbound(const int* __restrict__ batch, int* __restrict__ gptr) {
  int n = blockIdx.x * 256 + threadIdx.x;
  int b = batch[n];
  int prev = (n == 0) ? -1 : batch[n - 1];
  for (int g = prev + 1; g <= b; ++g) gptr[g] = n;
  if (n == NN - 1) {
    for (int g = b + 1; g <= NG; ++g) gptr[g] = NN;
  }
}

// ------ fused pull-aggregate + MFMA dual-linear + BN stats (EXACT R11/R15 body) ------
__global__ __launch_bounds__(256) void k_agglin(
    const int* __restrict__ rowptr, const uint2* __restrict__ colw,
    const __half* __restrict__ hIn, const float* __restrict__ Wrel,
    const float* __restrict__ brel, const float* __restrict__ Wroot,
    __half* __restrict__ hPre, double* __restrict__ stats) {
  __shared__ __half sA[4][1024];      // per-wave 32x32 f16 agg tile (XOR-swizzled)
  __shared__ uint2 sE[256];           // staged edge records
  __shared__ double rS[256], rQ[256];
  int t = threadIdx.x;
  int wv = t >> 6, lane = t & 63;
  int c = lane & 31, hi = lane >> 5, grp = t >> 5;
  char* myA = (char*)sA[wv];

  // B fragments in registers: B[k][c], k = 16m + hi*8 + j
  half8 bfr[4];
#pragma unroll
  for (int m = 0; m < 4; ++m)
#pragma unroll
    for (int j = 0; j < 8; ++j) {
      int k = 16 * m + hi * 8 + j;
      float w = (k < 32) ? Wrel[c * 32 + k] : Wroot[c * 32 + (k - 32)];
      bfr[m][j] = (_Float16)w;
    }
  float bias = brel[c];
  double aS = 0.0, aQ = 0.0;

  for (int tile = blockIdx.x * 4 + wv; tile < NN / 32; tile += gridDim.x * 4) {
    int nbase = tile * 32;
    // ---- gather: 16 rounds x 2 nodes (one per 32-lane group) ----
    for (int r = 0; r < 16; ++r) {
      int node = 2 * r + hi;
      int n = nbase + node;
      int r0 = rowptr[n], r1 = rowptr[n + 1];
      float acc = 0.f;
      for (int j = r0; j < r1; j += 32) {
        int m_ = r1 - j; if (m_ > 32) m_ = 32;
        uint2 cw = make_uint2(0u, 0u);             // pad: src=0 row, w=+0
        if (c < m_) cw = colw[j + c];
        sE[t] = cw;                                // same-wave LDS
        int mm = (m_ + 7) & ~7;
        for (int i = 0; i < mm; i += 8) {
          const uint4* eb4 = (const uint4*)&sE[grp * 32 + i];
          uint4 q0 = eb4[0], q1 = eb4[1], q2 = eb4[2], q3 = eb4[3];
          // 8 independent 2 B gathers -> 8 loads in flight
          float h0 = __half2float(hIn[(size_t)q0.x * 32 + c]);
          float h1 = __half2float(hIn[(size_t)q0.z * 32 + c]);
          float h2 = __half2float(hIn[(size_t)q1.x * 32 + c]);
          float h3 = __half2float(hIn[(size_t)q1.z * 32 + c]);
          float h4 = __half2float(hIn[(size_t)q2.x * 32 + c]);
          float h5 = __half2float(hIn[(size_t)q2.z * 32 + c]);
          float h6 = __half2float(hIn[(size_t)q3.x * 32 + c]);
          float h7 = __half2float(hIn[(size_t)q3.z * 32 + c]);
          acc = fmaf(__uint_as_float(q0.y), h0, acc);
          acc = fmaf(__uint_as_float(q0.w), h1, acc);
          acc = fmaf(__uint_as_float(q1.y), h2, acc);
          acc = fmaf(__uint_as_float(q1.w), h3, acc);
          acc = fmaf(__uint_as_float(q2.y), h4, acc);
          acc = fmaf(__uint_as_float(q2.w), h5, acc);
          acc = fmaf(__uint_as_float(q3.y), h6, acc);
          acc = fmaf(__uint_as_float(q3.w), h7, acc);
        }
      }
      // write acc to swizzled f16 tile: logical (node, k=c)
      int bw = (node * 64 + c * 2) ^ ((node & 7) << 4);
      *(__half*)(myA + bw) = __float2half(acc);
    }
    // ---- MFMA epilogue (wave-private; same-wave LDS ordering) ----
    f32x16 d;
#pragma unroll
    for (int r = 0; r < 16; ++r) d[r] = bias;
#pragma unroll
    for (int m = 0; m < 4; ++m) {
      half8 a;
      if (m < 2) {
        int node = c;                               // A row = lane&31
        int br = (node * 64 + (16 * m + hi * 8) * 2) ^ ((node & 7) << 4);
        a = *(const half8*)(myA + br);
      } else {
        int chb = 16 * (m - 2) + hi * 8;            // h channel base
        a = *(const half8*)(hIn + (size_t)(nbase + c) * 32 + chb);
      }
      d = __builtin_amdgcn_mfma_f32_32x32x16_f16(a, bfr[m], d, 0, 0, 0);
    }
    // ---- store + BN stats; D: col=lane&31, row=(r&3)+8*(r>>2)+4*hi ----
#pragma unroll
    for (int r = 0; r < 16; ++r) {
      int node = (r & 3) + 8 * (r >> 2) + 4 * hi;
      float v = d[r];
      hPre[(size_t)(nbase + node) * 32 + c] = __float2half(v);
      aS += v; aQ += (double)v * v;
    }
  }
  rS[t] = aS; rQ[t] = aQ;
  __syncthreads();
  for (int s = 128; s >= 32; s >>= 1) {
    if (t < s) { rS[t] += rS[t + s]; rQ[t] += rQ[t + s]; }
    __syncthreads();
  }
  if (t < 32) {
    atomicAdd(&stats[t], rS[t]);
    atomicAdd(&stats[32 + t], rQ[t]);
  }
}

// ---------------- finalize BN ----------------
__global__ void k_bnfin(const double* __restrict__ stats, const float* __restrict__ gamma,
                        const float* __restrict__ beta, float* __restrict__ ss) {
  int c = threadIdx.x;
  double mean = stats[c] * (1.0 / NN);
  double var = stats[32 + c] * (1.0 / NN) - mean * mean;
  float scale = gamma[c] * (float)(1.0 / sqrt(var + 1e-5));
  ss[c] = scale;
  ss[32 + c] = beta[c] - (float)mean * scale;
}

// ---------------- BN apply + ReLU (layer 1) ----------------
__global__ __launch_bounds__(256) void k_apply(const __half* __restrict__ in,
    const float* __restrict__ ss, __half* __restrict__ outp) {
  __shared__ float s0[32], s1[32];
  int t = threadIdx.x;
  if (t < 32) { s0[t] = ss[t]; s1[t] = ss[32 + t]; }
  __syncthreads();
  int idx = blockIdx.x * 256 + t;
  int c = idx & 31;
  float v = fmaxf(fmaf(__half2float(in[idx]), s0[c], s1[c]), 0.f);
  outp[idx] = __float2half(v);
}

// ------- layer-2 BN apply + ReLU + segment-max pool (half2, 4 node-slots) -------
__global__ __launch_bounds__(256) void k_pool(const __half* __restrict__ hB,
    const float* __restrict__ ss, const int* __restrict__ gptr, float* __restrict__ pooled) {
  int t = threadIdx.x;
  int wv = t >> 6, lane = t & 63;
  int p = lane >> 4, cl = lane & 15;          // 4 nodes in flight, 2 ch/lane
  float s0x = ss[2 * cl], s0y = ss[2 * cl + 1];
  float s1x = ss[32 + 2 * cl], s1y = ss[32 + 2 * cl + 1];
  int g = blockIdx.x * 4 + wv;                // grid 4096 x 4 waves = NG exactly
  int a = gptr[g], b = gptr[g + 1];
  float mx = 0.f, my = 0.f;                   // post-ReLU max >= 0
  for (int n = a + p; n < b; n += 4) {
    float2 hv = __half22float2(*(const __half2*)(hB + (size_t)n * 32 + 2 * cl));
    mx = fmaxf(mx, fmaf(hv.x, s0x, s1x));
    my = fmaxf(my, fmaf(hv.y, s0y, s1y));
  }
  mx = fmaxf(mx, __shfl_xor(mx, 16, 64)); my = fmaxf(my, __shfl_xor(my, 16, 64));
  mx = fmaxf(mx, __shfl_xor(mx, 32, 64)); my = fmaxf(my, __shfl_xor(my, 32, 64));
  if (p == 0) *(float2*)&pooled[g * 32 + 2 * cl] = make_float2(mx, my);
}

// ---------------- MLP head ----------------
__global__ __launch_bounds__(256) void k_head(const float* __restrict__ pooled,
    const float* __restrict__ W1, const float* __restrict__ b1,
    const float* __restrict__ W2, const float* __restrict__ b2, float* __restrict__ out) {
  __shared__ float sW1[64 * 33], sW2[10 * 65], sb1[64], sb2[10];
  __shared__ float sHid[4][64];
  int t = threadIdx.x;
  for (int i = t; i < 2048; i += 256) sW1[(i >> 5) * 33 + (i & 31)] = W1[i];
  for (int i = t; i < 640; i += 256) sW2[(i >> 6) * 65 + (i & 63)] = W2[i];
  if (t < 64) sb1[t] = b1[t];
  if (t < 10) sb2[t] = b2[t];
  __syncthreads();
  int w = t >> 6, lane = t & 63;
  for (int g = blockIdx.x * 4 + w; g < NG; g += gridDim.x * 4) {
    float pv = (lane < 32) ? pooled[g * 32 + lane] : 0.f;
    float acc = sb1[lane];
#pragma unroll
    for (int k = 0; k < 32; ++k)
      acc = fmaf(__shfl(pv, k, 64), sW1[lane * 33 + k], acc);
    acc = fmaxf(acc, 0.f);
    sHid[w][lane] = acc;
    __syncthreads();
    if (lane < 10) {
      float o = sb2[lane];
#pragma unroll
      for (int j = 0; j < 64; ++j) o = fmaf(sHid[w][j], sW2[lane * 65 + j], o);
      out[g * 10 + lane] = o;
    }
    __syncthreads();
  }
}

extern "C" void kernel_launch(void* const* d_in, const int* in_sizes, int n_in,
                              void* d_out, int out_size, void* d_ws, size_t ws_size,
                              hipStream_t stream) {
  const float* x      = (const float*)d_in[0];
  const int*   ei     = (const int*)d_in[1];
  const float* ea     = (const float*)d_in[2];
  const int*   batch  = (const int*)d_in[3];
  const float* W_emb  = (const float*)d_in[4];
  const float* b_emb  = (const float*)d_in[5];
  const float* W_rel  = (const float*)d_in[6];
  const float* b_rel  = (const float*)d_in[7];
  const float* W_root = (const float*)d_in[8];
  const float* gamma  = (const float*)d_in[9];
  const float* beta   = (const float*)d_in[10];
  const float* W1     = (const float*)d_in[11];
  const float* b1     = (const float*)d_in[12];
  const float* W2     = (const float*)d_in[13];
  const float* b2     = (const float*)d_in[14];
  float* out = (float*)d_out;

  // ---- workspace layout (~204 MiB of 256 MiB) ----
  char* ws = (char*)d_ws;
  size_t off = 0;
  __half* hA    = (__half*)(ws + off); off += (size_t)NN * 32 * 2;          // 64 MiB
  uint2*  colw  = (uint2*)(ws + off);  off += (size_t)NE * 8;               // 64 MiB
  uint2*  bsw   = (uint2*)(ws + off);                                        // 64 MiB
  __half* hB    = (__half*)(ws + off);                                       // ALIASES bsw (dead before hB written)
  off += (size_t)NE * 8;
  int*    rowptr= (int*)(ws + off);    off += ((size_t)NN + 64) * 4;        // 4 MiB
  int*    hist  = (int*)(ws + off);    off += (size_t)NBUCK * PBLK * 4;     // 4 MiB
  int*    tot   = (int*)(ws + off);    off += NBUCK * 4;                    // 16 KiB
  int*    gbase = (int*)(ws + off);    off += (NBUCK + 64) * 4;             // ~16 KiB
  int*    gptr  = (int*)(ws + off);    off += ((size_t)NG + 64) * 4;
  float*  pooled= (float*)(ws + off);                                        // 2 MiB
  double* stats = (double*)d_out;                   // overwritten by k_head later
  float*  ss0   = (float*)((char*)d_out + 512);
  float*  ss1   = (float*)((char*)d_out + 768);

  k_embed<<<NN * 32 / 256, 256, 0, stream>>>(x, W_emb, b_emb, hA);

  // ---- radix-partition CSR build (4096 buckets; LDS-staged finalize) ----
  k_pcnt <<<PBLK, 1024, 0, stream>>>(ei + NE, hist);
  k_scanA<<<NBUCK, 256, 0, stream>>>(hist, tot);
  k_scanB<<<1, 256, 0, stream>>>(tot, gbase);
  k_part <<<PBLK, 1024, 0, stream>>>(ei, ea, hist, gbase, bsw);
  k_fillD2<<<NBUCK, 256, 0, stream>>>(gbase, bsw, rowptr, colw);
  k_gbound<<<NN / 256, 256, 0, stream>>>(batch, gptr);

  // ---- layer 1: agglin(hA -> hB), BN stats, apply BN+ReLU (hB -> hA) ----
  (void)hipMemsetAsync(stats, 0, 64 * 8, stream);
  k_agglin<<<2048, 256, 0, stream>>>(rowptr, colw, hA, W_rel, b_rel, W_root, hB, stats);
  k_bnfin<<<1, 32, 0, stream>>>(stats, gamma, beta, ss0);
  k_apply<<<NN * 32 / 256, 256, 0, stream>>>(hB, ss0, hA);

  // ---- layer 2: agglin(hA -> hB), BN stats, fused pool ----
  (void)hipMemsetAsync(stats, 0, 64 * 8, stream);
  k_agglin<<<2048, 256, 0, stream>>>(rowptr, colw, hA, W_rel + 1024, b_rel + 32,
                                     W_root + 1024, hB, stats);
  k_bnfin<<<1, 32, 0, stream>>>(stats, gamma + 32, beta + 32, ss1);

  k_pool<<<NG / 4, 256, 0, stream>>>(hB, ss1, gptr, pooled);
  k_head<<<1024, 256, 0, stream>>>(pooled, W1, b1, W2, b2, out);
}

// Round 24
// 937.395 us; speedup vs baseline: 3.5708x; 1.0401x over previous
//
#include <hip/hip_runtime.h>
#include <hip/hip_fp16.h>

#define NN 1048576   // nodes
#define NE 8388608   // edges
#define NG 16384     // graphs
#define NBUCK 4096   // dst buckets (256 nodes each)
#define BSH 8        // bucket shift (node = bucket*256 + dlocal)
#define PBLK 256     // partition blocks (1 per CU)
#define EPB (NE / PBLK)  // edges per partition block = 32768
#define SCAP 2600    // LDS record capacity per bucket (mean 2048, +12 sigma)

typedef _Float16 half8 __attribute__((ext_vector_type(8)));
typedef float f32x16 __attribute__((ext_vector_type(16)));

// ---------------- node embedding: hA = f16(x @ W_emb^T + b_emb) ----------------
__global__ __launch_bounds__(256) void k_embed(const float* __restrict__ x,
    const float* __restrict__ W, const float* __restrict__ b, __half* __restrict__ h) {
  __shared__ float sW[160];
  __shared__ float sb[32];
  int t = threadIdx.x;
  if (t < 160) sW[t] = W[t];
  if (t < 32) sb[t] = b[t];
  __syncthreads();
  int idx = blockIdx.x * 256 + t;      // (node, channel)
  int c = idx & 31, n = idx >> 5;
  const float* xr = x + n * 5;
  float acc = sb[c];
#pragma unroll
  for (int k = 0; k < 5; ++k) acc = fmaf(xr[k], sW[c * 5 + k], acc);
  h[idx] = __float2half(acc);
}

// ---------------- radix pass 1: per-(block,bucket) histogram (1024 threads) ----------------
__global__ __launch_bounds__(1024) void k_pcnt(const int* __restrict__ dst, int* __restrict__ hist) {
  __shared__ int lh[NBUCK];            // 16 KB
  int t = threadIdx.x;
#pragma unroll
  for (int k = 0; k < 4; ++k) lh[t + k * 1024] = 0;
  __syncthreads();
  int base = blockIdx.x * EPB;
  for (int e = base + t; e < base + EPB; e += 1024)
    atomicAdd(&lh[dst[e] >> BSH], 1);
  __syncthreads();
#pragma unroll
  for (int k = 0; k < 4; ++k) {
    int b = t + k * 1024;
    hist[b * PBLK + blockIdx.x] = lh[b];           // assign, no atomics
  }
}

// ---------------- radix pass 2a: per-bucket row scan (PBLK=256 cols) + totals ----------------
__global__ __launch_bounds__(256) void k_scanA(int* __restrict__ hist, int* __restrict__ tot) {
  __shared__ int s2[256];
  int b = blockIdx.x, t = threadIdx.x;
  int v = hist[b * PBLK + t];
  s2[t] = v; __syncthreads();
  for (int st = 1; st < 256; st <<= 1) {
    int a = (t >= st) ? s2[t - st] : 0; __syncthreads(); s2[t] += a; __syncthreads();
  }
  hist[b * PBLK + t] = s2[t] - v;
  if (t == 255) tot[b] = s2[255];
}

// ---------------- radix pass 2b: scan 4096 bucket totals -> gbase ----------------
__global__ __launch_bounds__(256) void k_scanB(const int* __restrict__ tot, int* __restrict__ gbase) {
  __shared__ int s2[256];
  int t = threadIdx.x;
  int v[16]; int tsum = 0;
#pragma unroll
  for (int j = 0; j < 16; ++j) { v[j] = tot[t * 16 + j]; tsum += v[j]; }
  s2[t] = tsum; __syncthreads();
  for (int st = 1; st < 256; st <<= 1) {
    int a = (t >= st) ? s2[t - st] : 0; __syncthreads(); s2[t] += a; __syncthreads();
  }
  int ex = s2[t] - tsum;
#pragma unroll
  for (int j = 0; j < 16; ++j) { gbase[t * 16 + j] = ex; ex += v[j]; }
  if (t == 255) gbase[NBUCK] = ex;                  // == NE
}

// ---- radix pass 3: partition (1024 threads, 16 waves/CU); 8-record runs ----
__global__ __launch_bounds__(1024) void k_part(const int* __restrict__ ei, const float* __restrict__ ew,
                                               const int* __restrict__ hist, const int* __restrict__ gbase,
                                               uint2* __restrict__ bsw) {
  __shared__ int cur[NBUCK];           // 16 KB
  int t = threadIdx.x, blk = blockIdx.x;
#pragma unroll
  for (int k = 0; k < 4; ++k) {
    int b = t + k * 1024;
    cur[b] = gbase[b] + hist[b * PBLK + blk];
  }
  __syncthreads();
  int base = blk * EPB;
  for (int e = base + t; e < base + EPB; e += 1024) {
    int src = ei[e];
    int d   = ei[NE + e];
    unsigned wb = __float_as_uint(ew[e]);
    int b = d >> BSH;
    int pos = atomicAdd(&cur[b], 1);
    bsw[pos] = make_uint2(((unsigned)src << BSH) | (unsigned)(d & 255), wb);
  }
}

// ------- CSR finalize: LDS-staged per-bucket sort -> rowptr + L2-local colw scatter -------
__global__ __launch_bounds__(256) void k_fillD2(const int* __restrict__ gbase, const uint2* __restrict__ bsw,
                                                int* __restrict__ rowptr, uint2* __restrict__ colw) {
  __shared__ uint2 rec[SCAP];          // 20.8 KB record staging
  __shared__ int loc[256];
  __shared__ int s2[256];
  int t = threadIdx.x, b = blockIdx.x;
  int beg = gbase[b], end = gbase[b + 1], gb = beg;
  int cnt = end - beg;
  bool staged = (cnt <= SCAP);         // block-uniform; fallback path for impossible overflow
  loc[t] = 0;
  if (staged) {
    for (int i = t; i < cnt; i += 256) rec[i] = bsw[beg + i];   // one coalesced read
  }
  __syncthreads();
  for (int i = t; i < cnt; i += 256) {
    unsigned rx = staged ? rec[i].x : bsw[beg + i].x;
    atomicAdd(&loc[rx & 255], 1);
  }
  __syncthreads();
  int v = loc[t];
  s2[t] = v; __syncthreads();
  for (int st = 1; st < 256; st <<= 1) {
    int a = (t >= st) ? s2[t - st] : 0; __syncthreads(); s2[t] += a; __syncthreads();
  }
  int base_t = s2[t] - v;
  rowptr[(b << BSH) + t] = gb + base_t;            // coalesced rowptr write
  loc[t] = base_t;                                 // running cursor per node
  if (b == NBUCK - 1 && t == 255) rowptr[NN] = NE;
  __syncthreads();
  for (int i = t; i < cnt; i += 256) {
    uint2 r = staged ? rec[i] : bsw[beg + i];
    int p = atomicAdd(&loc[r.x & 255], 1);
    colw[gb + p] = make_uint2(r.x >> BSH, r.y);    // scatter within 16 KB L2-resident span
  }
}

// ---------------- graph rowptr from sorted batch ----------------
__global__ __launch_bounds__(256) void k_gbound(const int* __restrict__ batch, int* __restrict__ gptr) {
  int n = blockIdx.x * 256 + threadIdx.x;
  int b = batch[n];
  int prev = (n == 0) ? -1 : batch[n - 1];
  for (int g = prev + 1; g <= b; ++g) gptr[g] = n;
  if (n == NN - 1) {
    for (int g = b + 1; g <= NG; ++g) gptr[g] = NN;
  }
}

// ------ fused pull-aggregate + MFMA dual-linear + BN stats; 16-deep gather ------
__global__ __launch_bounds__(256) void k_agglin(
    const int* __restrict__ rowptr, const uint2* __restrict__ colw,
    const __half* __restrict__ hIn, const float* __restrict__ Wrel,
    const float* __restrict__ brel, const float* __restrict__ Wroot,
    __half* __restrict__ hPre, double* __restrict__ stats) {
  __shared__ __half sA[4][1024];      // per-wave 32x32 f16 agg tile (XOR-swizzled)
  __shared__ uint2 sE[256];           // staged edge records
  __shared__ double rS[256], rQ[256];
  int t = threadIdx.x;
  int wv = t >> 6, lane = t & 63;
  int c = lane & 31, hi = lane >> 5, grp = t >> 5;
  char* myA = (char*)sA[wv];

  // B fragments in registers: B[k][c], k = 16m + hi*8 + j
  half8 bfr[4];
#pragma unroll
  for (int m = 0; m < 4; ++m)
#pragma unroll
    for (int j = 0; j < 8; ++j) {
      int k = 16 * m + hi * 8 + j;
      float w = (k < 32) ? Wrel[c * 32 + k] : Wroot[c * 32 + (k - 32)];
      bfr[m][j] = (_Float16)w;
    }
  float bias = brel[c];
  float aS = 0.f, aQ = 0.f;           // f32 partials (proven safe R13); f64 at block reduce

  for (int tile = blockIdx.x * 4 + wv; tile < NN / 32; tile += gridDim.x * 4) {
    int nbase = tile * 32;
    // ---- gather: 16 rounds x 2 nodes (one per 32-lane group) ----
    for (int r = 0; r < 16; ++r) {
      int node = 2 * r + hi;
      int n = nbase + node;
      int r0 = rowptr[n], r1 = rowptr[n + 1];
      float acc = 0.f;
      for (int j = r0; j < r1; j += 32) {
        int m_ = r1 - j; if (m_ > 32) m_ = 32;
        uint2 cw = make_uint2(0u, 0u);             // pad: src=0 row, w=+0
        if (c < m_) cw = colw[j + c];
        sE[t] = cw;                                // same-wave LDS (all 32 slots written)
        int mm = (m_ + 15) & ~15;                  // 16 or 32; pads are zero records
        for (int i = 0; i < mm; i += 16) {
          const uint4* eb4 = (const uint4*)&sE[grp * 32 + i];
          uint4 q0 = eb4[0], q1 = eb4[1], q2 = eb4[2], q3 = eb4[3];
          uint4 q4 = eb4[4], q5 = eb4[5], q6 = eb4[6], q7 = eb4[7];
          // 16 independent 2 B gathers -> 16 loads in flight
          float h0 = __half2float(hIn[(size_t)q0.x * 32 + c]);
          float h1 = __half2float(hIn[(size_t)q0.z * 32 + c]);
          float h2 = __half2float(hIn[(size_t)q1.x * 32 + c]);
          float h3 = __half2float(hIn[(size_t)q1.z * 32 + c]);
          float h4 = __half2float(hIn[(size_t)q2.x * 32 + c]);
          float h5 = __half2float(hIn[(size_t)q2.z * 32 + c]);
          float h6 = __half2float(hIn[(size_t)q3.x * 32 + c]);
          float h7 = __half2float(hIn[(size_t)q3.z * 32 + c]);
          float h8 = __half2float(hIn[(size_t)q4.x * 32 + c]);
          float h9 = __half2float(hIn[(size_t)q4.z * 32 + c]);
          float hA_ = __half2float(hIn[(size_t)q5.x * 32 + c]);
          float hB_ = __half2float(hIn[(size_t)q5.z * 32 + c]);
          float hC_ = __half2float(hIn[(size_t)q6.x * 32 + c]);
          float hD_ = __half2float(hIn[(size_t)q6.z * 32 + c]);
          float hE_ = __half2float(hIn[(size_t)q7.x * 32 + c]);
          float hF_ = __half2float(hIn[(size_t)q7.z * 32 + c]);
          acc = fmaf(__uint_as_float(q0.y), h0, acc);
          acc = fmaf(__uint_as_float(q0.w), h1, acc);
          acc = fmaf(__uint_as_float(q1.y), h2, acc);
          acc = fmaf(__uint_as_float(q1.w), h3, acc);
          acc = fmaf(__uint_as_float(q2.y), h4, acc);
          acc = fmaf(__uint_as_float(q2.w), h5, acc);
          acc = fmaf(__uint_as_float(q3.y), h6, acc);
          acc = fmaf(__uint_as_float(q3.w), h7, acc);
          acc = fmaf(__uint_as_float(q4.y), h8, acc);
          acc = fmaf(__uint_as_float(q4.w), h9, acc);
          acc = fmaf(__uint_as_float(q5.y), hA_, acc);
          acc = fmaf(__uint_as_float(q5.w), hB_, acc);
          acc = fmaf(__uint_as_float(q6.y), hC_, acc);
          acc = fmaf(__uint_as_float(q6.w), hD_, acc);
          acc = fmaf(__uint_as_float(q7.y), hE_, acc);
          acc = fmaf(__uint_as_float(q7.w), hF_, acc);
        }
      }
      // write acc to swizzled f16 tile: logical (node, k=c)
      int bw = (node * 64 + c * 2) ^ ((node & 7) << 4);
      *(__half*)(myA + bw) = __float2half(acc);
    }
    // ---- MFMA epilogue (wave-private; same-wave LDS ordering) ----
    f32x16 d;
#pragma unroll
    for (int r = 0; r < 16; ++r) d[r] = bias;
#pragma unroll
    for (int m = 0; m < 4; ++m) {
      half8 a;
      if (m < 2) {
        int node = c;                               // A row = lane&31
        int br = (node * 64 + (16 * m + hi * 8) * 2) ^ ((node & 7) << 4);
        a = *(const half8*)(myA + br);
      } else {
        int chb = 16 * (m - 2) + hi * 8;            // h channel base
        a = *(const half8*)(hIn + (size_t)(nbase + c) * 32 + chb);
      }
      d = __builtin_amdgcn_mfma_f32_32x32x16_f16(a, bfr[m], d, 0, 0, 0);
    }
    // ---- store + BN stats; D: col=lane&31, row=(r&3)+8*(r>>2)+4*hi ----
#pragma unroll
    for (int r = 0; r < 16; ++r) {
      int node = (r & 3) + 8 * (r >> 2) + 4 * hi;
      float v = d[r];
      hPre[(size_t)(nbase + node) * 32 + c] = __float2half(v);
      aS += v; aQ += v * v;
    }
  }
  rS[t] = (double)aS; rQ[t] = (double)aQ;
  __syncthreads();
  for (int s = 128; s >= 32; s >>= 1) {
    if (t < s) { rS[t] += rS[t + s]; rQ[t] += rQ[t + s]; }
    __syncthreads();
  }
  if (t < 32) {
    atomicAdd(&stats[t], rS[t]);
    atomicAdd(&stats[32 + t], rQ[t]);
  }
}

// ---------------- finalize BN ----------------
__global__ void k_bnfin(const double* __restrict__ stats, const float* __restrict__ gamma,
                        const float* __restrict__ beta, float* __restrict__ ss) {
  int c = threadIdx.x;
  double mean = stats[c] * (1.0 / NN);
  double var = stats[32 + c] * (1.0 / NN) - mean * mean;
  float scale = gamma[c] * (float)(1.0 / sqrt(var + 1e-5));
  ss[c] = scale;
  ss[32 + c] = beta[c] - (float)mean * scale;
}

// ---------------- BN apply + ReLU (layer 1) ----------------
__global__ __launch_bounds__(256) void k_apply(const __half* __restrict__ in,
    const float* __restrict__ ss, __half* __restrict__ outp) {
  __shared__ float s0[32], s1[32];
  int t = threadIdx.x;
  if (t < 32) { s0[t] = ss[t]; s1[t] = ss[32 + t]; }
  __syncthreads();
  int idx = blockIdx.x * 256 + t;
  int c = idx & 31;
  float v = fmaxf(fmaf(__half2float(in[idx]), s0[c], s1[c]), 0.f);
  outp[idx] = __float2half(v);
}

// ------- layer-2 BN apply + ReLU + segment-max pool (half2, 4 node-slots) -------
__global__ __launch_bounds__(256) void k_pool(const __half* __restrict__ hB,
    const float* __restrict__ ss, const int* __restrict__ gptr, float* __restrict__ pooled) {
  int t = threadIdx.x;
  int wv = t >> 6, lane = t & 63;
  int p = lane >> 4, cl = lane & 15;          // 4 nodes in flight, 2 ch/lane
  float s0x = ss[2 * cl], s0y = ss[2 * cl + 1];
  float s1x = ss[32 + 2 * cl], s1y = ss[32 + 2 * cl + 1];
  int g = blockIdx.x * 4 + wv;                // grid 4096 x 4 waves = NG exactly
  int a = gptr[g], b = gptr[g + 1];
  float mx = 0.f, my = 0.f;                   // post-ReLU max >= 0
  for (int n = a + p; n < b; n += 4) {
    float2 hv = __half22float2(*(const __half2*)(hB + (size_t)n * 32 + 2 * cl));
    mx = fmaxf(mx, fmaf(hv.x, s0x, s1x));
    my = fmaxf(my, fmaf(hv.y, s0y, s1y));
  }
  mx = fmaxf(mx, __shfl_xor(mx, 16, 64)); my = fmaxf(my, __shfl_xor(my, 16, 64));
  mx = fmaxf(mx, __shfl_xor(mx, 32, 64)); my = fmaxf(my, __shfl_xor(my, 32, 64));
  if (p == 0) *(float2*)&pooled[g * 32 + 2 * cl] = make_float2(mx, my);
}

// ---------------- MLP head ----------------
__global__ __launch_bounds__(256) void k_head(const float* __restrict__ pooled,
    const float* __restrict__ W1, const float* __restrict__ b1,
    const float* __restrict__ W2, const float* __restrict__ b2, float* __restrict__ out) {
  __shared__ float sW1[64 * 33], sW2[10 * 65], sb1[64], sb2[10];
  __shared__ float sHid[4][64];
  int t = threadIdx.x;
  for (int i = t; i < 2048; i += 256) sW1[(i >> 5) * 33 + (i & 31)] = W1[i];
  for (int i = t; i < 640; i += 256) sW2[(i >> 6) * 65 + (i & 63)] = W2[i];
  if (t < 64) sb1[t] = b1[t];
  if (t < 10) sb2[t] = b2[t];
  __syncthreads();
  int w = t >> 6, lane = t & 63;
  for (int g = blockIdx.x * 4 + w; g < NG; g += gridDim.x * 4) {
    float pv = (lane < 32) ? pooled[g * 32 + lane] : 0.f;
    float acc = sb1[lane];
#pragma unroll
    for (int k = 0; k < 32; ++k)
      acc = fmaf(__shfl(pv, k, 64), sW1[lane * 33 + k], acc);
    acc = fmaxf(acc, 0.f);
    sHid[w][lane] = acc;
    __syncthreads();
    if (lane < 10) {
      float o = sb2[lane];
#pragma unroll
      for (int j = 0; j < 64; ++j) o = fmaf(sHid[w][j], sW2[lane * 65 + j], o);
      out[g * 10 + lane] = o;
    }
    __syncthreads();
  }
}

extern "C" void kernel_launch(void* const* d_in, const int* in_sizes, int n_in,
                              void* d_out, int out_size, void* d_ws, size_t ws_size,
                              hipStream_t stream) {
  const float* x      = (const float*)d_in[0];
  const int*   ei     = (const int*)d_in[1];
  const float* ea     = (const float*)d_in[2];
  const int*   batch  = (const int*)d_in[3];
  const float* W_emb  = (const float*)d_in[4];
  const float* b_emb  = (const float*)d_in[5];
  const float* W_rel  = (const float*)d_in[6];
  const float* b_rel  = (const float*)d_in[7];
  const float* W_root = (const float*)d_in[8];
  const float* gamma  = (const float*)d_in[9];
  const float* beta   = (const float*)d_in[10];
  const float* W1     = (const float*)d_in[11];
  const float* b1     = (const float*)d_in[12];
  const float* W2     = (const float*)d_in[13];
  const float* b2     = (const float*)d_in[14];
  float* out = (float*)d_out;

  // ---- workspace layout (~204 MiB of 256 MiB) ----
  char* ws = (char*)d_ws;
  size_t off = 0;
  __half* hA    = (__half*)(ws + off); off += (size_t)NN * 32 * 2;          // 64 MiB
  uint2*  colw  = (uint2*)(ws + off);  off += (size_t)NE * 8;               // 64 MiB
  uint2*  bsw   = (uint2*)(ws + off);                                        // 64 MiB
  __half* hB    = (__half*)(ws + off);                                       // ALIASES bsw (dead before hB written)
  off += (size_t)NE * 8;
  int*    rowptr= (int*)(ws + off);    off += ((size_t)NN + 64) * 4;        // 4 MiB
  int*    hist  = (int*)(ws + off);    off += (size_t)NBUCK * PBLK * 4;     // 4 MiB
  int*    tot   = (int*)(ws + off);    off += NBUCK * 4;                    // 16 KiB
  int*    gbase = (int*)(ws + off);    off += (NBUCK + 64) * 4;             // ~16 KiB
  int*    gptr  = (int*)(ws + off);    off += ((size_t)NG + 64) * 4;
  float*  pooled= (float*)(ws + off);                                        // 2 MiB
  double* stats = (double*)d_out;                   // overwritten by k_head later
  float*  ss0   = (float*)((char*)d_out + 512);
  float*  ss1   = (float*)((char*)d_out + 768);

  k_embed<<<NN * 32 / 256, 256, 0, stream>>>(x, W_emb, b_emb, hA);

  // ---- radix-partition CSR build (4096 buckets; LDS-staged finalize) ----
  k_pcnt <<<PBLK, 1024, 0, stream>>>(ei + NE, hist);
  k_scanA<<<NBUCK, 256, 0, stream>>>(hist, tot);
  k_scanB<<<1, 256, 0, stream>>>(tot, gbase);
  k_part <<<PBLK, 1024, 0, stream>>>(ei, ea, hist, gbase, bsw);
  k_fillD2<<<NBUCK, 256, 0, stream>>>(gbase, bsw, rowptr, colw);
  k_gbound<<<NN / 256, 256, 0, stream>>>(batch, gptr);

  // ---- layer 1: agglin(hA -> hB), BN stats, apply BN+ReLU (hB -> hA) ----
  (void)hipMemsetAsync(stats, 0, 64 * 8, stream);
  k_agglin<<<2048, 256, 0, stream>>>(rowptr, colw, hA, W_rel, b_rel, W_root, hB, stats);
  k_bnfin<<<1, 32, 0, stream>>>(stats, gamma, beta, ss0);
  k_apply<<<NN * 32 / 256, 256, 0, stream>>>(hB, ss0, hA);

  // ---- layer 2: agglin(hA -> hB), BN stats, fused pool ----
  (void)hipMemsetAsync(stats, 0, 64 * 8, stream);
  k_agglin<<<2048, 256, 0, stream>>>(rowptr, colw, hA, W_rel + 1024, b_rel + 32,
                                     W_root + 1024, hB, stats);
  k_bnfin<<<1, 32, 0, stream>>>(stats, gamma + 32, beta + 32, ss1);

  k_pool<<<NG / 4, 256, 0, stream>>>(hB, ss1, gptr, pooled);
  k_head<<<1024, 256, 0, stream>>>(pooled, W1, b1, W2, b2, out);
}